// Round 1
// baseline (530.813 us; speedup 1.0000x reference)
//
#include <hip/hip_runtime.h>
#include <math.h>

#define VOCAB 32000
#define D 256
#define NB 32
#define NEQ 5
#define SEQ 64

// ---------------------------------------------------------------------------
// Phase 1: sequential scan over 64 tokens. Single wave (64 threads).
// State: mm[256] (mean of memory), distributed 4 dims/lane.
// Per token emits: x_wm[256], u[32], vv[32], C  (closed-form foam coeffs).
// ---------------------------------------------------------------------------
__global__ __launch_bounds__(64) void foam_scan_kernel(
    const int* __restrict__ tokens,
    const float* __restrict__ E,
    const float* __restrict__ bubbles,
    const float* __restrict__ p_mdb,
    const float* __restrict__ p_ns,
    float* __restrict__ ws)
{
    const int l = threadIdx.x;      // 0..63
    const int b = l & 31;           // bubble owned by this lane (duplicated in halves)
    const int half = l >> 5;        // 0 or 1: which 128-dim half of the dot

    constexpr int BS = 260;         // padded row stride (floats) to spread banks
    __shared__ __align__(16) float bub[NB * BS];   // 33,280 B
    __shared__ __align__(16) float xwm_s[D];

    // load bubbles to LDS (row-major, padded)
    for (int r = 0; r < NB; ++r)
        *(float4*)&bub[r * BS + 4 * l] = *(const float4*)(bubbles + r * D + 4 * l);
    __syncthreads();

    // |bubbles_b|^2, per-lane for its bubble
    float bn2p = 0.f;
    {
        const float* brow = &bub[b * BS + half * 128];
        #pragma unroll
        for (int i = 0; i < 32; ++i) {
            float4 bv = *(const float4*)(brow + 4 * i);
            bn2p = fmaf(bv.x, bv.x, fmaf(bv.y, bv.y, fmaf(bv.z, bv.z, fmaf(bv.w, bv.w, bn2p))));
        }
    }
    float bn2 = bn2p + __shfl_xor(bn2p, 32);

    const float mdb  = p_mdb[0];
    const float sens = fabsf(p_ns[0]);
    const float scale = 0.0625f;    // 1/sqrt(256)

    float4 mm = make_float4(0.f, 0.f, 0.f, 0.f);

    float* ws_xwm = ws;                          // [SEQ][D]
    float* ws_u   = ws + SEQ * D;                // [SEQ][NB]
    float* ws_vv  = ws + SEQ * D + SEQ * NB;     // [SEQ][NB]
    float* ws_C   = ws + SEQ * D + 2 * SEQ * NB; // [SEQ]

    for (int t = 0; t < SEQ; ++t) {
        const int tok = tokens[t];
        float4 x = *(const float4*)(E + (long)tok * D + 4 * l);

        // fused reductions: dot(x,mm), |x|^2, |mm|^2
        float pd = x.x * mm.x + x.y * mm.y + x.z * mm.z + x.w * mm.w;
        float px = x.x * x.x + x.y * x.y + x.z * x.z + x.w * x.w;
        float pm = mm.x * mm.x + mm.y * mm.y + mm.z * mm.z + mm.w * mm.w;
        #pragma unroll
        for (int off = 32; off; off >>= 1) {
            pd += __shfl_xor(pd, off);
            px += __shfl_xor(px, off);
            pm += __shfl_xor(pm, off);
        }

        const float x_norm   = sqrtf(px) + 1e-10f;
        const float mem_norm = sqrtf(pm) + 1e-10f;
        const float nov = (mem_norm > 1e-8f) ? (1.f - pd / (x_norm * mem_norm)) : 1.f;
        const float decay = 1.f / (1.f + expf(sens * nov - mdb));

        float4 xw;
        xw.x = fmaf(decay, mm.x, x.x);
        xw.y = fmaf(decay, mm.y, x.y);
        xw.z = fmaf(decay, mm.z, x.z);
        xw.w = fmaf(decay, mm.w, x.w);
        const float q = px + 2.f * decay * pd + decay * decay * pm;   // |x_wm|^2

        *(float4*)&xwm_s[4 * l] = xw;
        __syncthreads();

        // c_b = bubbles_b . x_wm   (lane = (b, half), 128 dims each)
        float cp = 0.f;
        {
            const float* brow = &bub[b * BS + half * 128];
            const float* xh = &xwm_s[half * 128];
            #pragma unroll
            for (int i = 0; i < 32; ++i) {
                float4 bv = *(const float4*)(brow + 4 * i);
                float4 xv = *(const float4*)(xh + 4 * i);
                cp = fmaf(bv.x, xv.x, fmaf(bv.y, xv.y, fmaf(bv.z, xv.z, fmaf(bv.w, xv.w, cp))));
            }
        }
        const float c = cp + __shfl_xor(cp, 32);

        // equilibrium: alpha_b = prod(1 - w_k);  s_b = alpha*b + (1-alpha)*x_wm
        float alpha = 1.f;
        float w = 0.f;
        #pragma unroll
        for (int k = 0; k <= NEQ; ++k) {
            float dv = (alpha * c + (1.f - alpha) * q) * scale;
            float mx = dv;
            #pragma unroll
            for (int off = 16; off; off >>= 1) mx = fmaxf(mx, __shfl_xor(mx, off));
            float ev = expf(dv - mx);
            float sm = ev;
            #pragma unroll
            for (int off = 16; off; off >>= 1) sm += __shfl_xor(sm, off);
            w = ev / sm;
            if (k < NEQ) alpha *= (1.f - w);
        }
        const float p = w;   // final softmax = output dist

        const float oma = 1.f - alpha;
        const float s2 = alpha * alpha * bn2 + 2.f * alpha * oma * c + oma * oma * q;
        const float nrm = sqrtf(s2) + 1e-10f;
        const float g = p / (nrm * nrm);
        const float uu  = g * alpha * alpha;
        const float vv2 = 2.f * g * alpha * oma;
        float Cpart = g * oma * oma;
        #pragma unroll
        for (int off = 16; off; off >>= 1) Cpart += __shfl_xor(Cpart, off);
        float suma = alpha;
        #pragma unroll
        for (int off = 16; off; off >>= 1) suma += __shfl_xor(suma, off);

        // emit per-token coefficients
        *(float4*)(ws_xwm + t * D + 4 * l) = xw;
        if (half == 0) ws_u[t * NB + b] = uu;
        else           ws_vv[t * NB + b] = vv2;
        if (l == 0)    ws_C[t] = Cpart;

        // mm update: mean(s) = (1/32) * (sum_b alpha_b*bubbles_b + sum_b(1-alpha_b)*x_wm)
        float4 acc = make_float4(0.f, 0.f, 0.f, 0.f);
        #pragma unroll
        for (int bb = 0; bb < NB; ++bb) {
            const float ab = __shfl(alpha, bb);
            float4 bv = *(const float4*)&bub[bb * BS + 4 * l];
            acc.x = fmaf(ab, bv.x, acc.x);
            acc.y = fmaf(ab, bv.y, acc.y);
            acc.z = fmaf(ab, bv.z, acc.z);
            acc.w = fmaf(ab, bv.w, acc.w);
        }
        const float msc = (32.f - suma) * (1.f / 32.f);
        const float omd = 1.f - decay;
        mm.x = decay * mm.x + omd * fmaf(msc, xw.x, acc.x * (1.f / 32.f));
        mm.y = decay * mm.y + omd * fmaf(msc, xw.y, acc.y * (1.f / 32.f));
        mm.z = decay * mm.z + omd * fmaf(msc, xw.z, acc.z * (1.f / 32.f));
        mm.w = decay * mm.w + omd * fmaf(msc, xw.w, acc.w * (1.f / 32.f));

        __syncthreads();
    }
}

// ---------------------------------------------------------------------------
// Phase 2: logits[t][v] = A + h*B + h^2*C.
// One thread per vocab row; G[32] = e.bubbles_b, h[64] = e.x_wm_t.
// ---------------------------------------------------------------------------
__global__ __launch_bounds__(128) void foam_logits_kernel(
    const float* __restrict__ E,
    const float* __restrict__ bubbles,
    const float* __restrict__ ws,
    float* __restrict__ out)
{
    __shared__ __align__(16) float bub[NB * D];    // 32 KB
    __shared__ __align__(16) float xwm[SEQ * D];   // 64 KB
    __shared__ __align__(16) float us[SEQ * NB];   // 8 KB
    __shared__ __align__(16) float vs[SEQ * NB];   // 8 KB
    __shared__ float Cs[SEQ];

    const int tid = threadIdx.x;
    const float* ws_xwm = ws;
    const float* ws_u   = ws + SEQ * D;
    const float* ws_vv  = ws + SEQ * D + SEQ * NB;
    const float* ws_C   = ws + SEQ * D + 2 * SEQ * NB;

    for (int i = tid; i < NB * D / 4; i += 128)  ((float4*)bub)[i] = ((const float4*)bubbles)[i];
    for (int i = tid; i < SEQ * D / 4; i += 128) ((float4*)xwm)[i] = ((const float4*)ws_xwm)[i];
    for (int i = tid; i < SEQ * NB / 4; i += 128) ((float4*)us)[i] = ((const float4*)ws_u)[i];
    for (int i = tid; i < SEQ * NB / 4; i += 128) ((float4*)vs)[i] = ((const float4*)ws_vv)[i];
    if (tid < SEQ) Cs[tid] = ws_C[tid];
    __syncthreads();

    const int v = blockIdx.x * 128 + tid;
    const float4* erow = (const float4*)(E + (long)v * D);

    float G[NB];
    float h[SEQ];
    #pragma unroll
    for (int i = 0; i < NB; ++i) G[i] = 0.f;
    #pragma unroll
    for (int i = 0; i < SEQ; ++i) h[i] = 0.f;

    for (int dc = 0; dc < D / 4; ++dc) {
        const float4 e = erow[dc];
        #pragma unroll
        for (int bb = 0; bb < NB; ++bb) {
            float4 bv = ((const float4*)bub)[bb * (D / 4) + dc];
            G[bb] = fmaf(e.x, bv.x, fmaf(e.y, bv.y, fmaf(e.z, bv.z, fmaf(e.w, bv.w, G[bb]))));
        }
        #pragma unroll
        for (int t = 0; t < SEQ; ++t) {
            float4 xv = ((const float4*)xwm)[t * (D / 4) + dc];
            h[t] = fmaf(e.x, xv.x, fmaf(e.y, xv.y, fmaf(e.z, xv.z, fmaf(e.w, xv.w, h[t]))));
        }
    }

    float G2[NB];
    #pragma unroll
    for (int i = 0; i < NB; ++i) G2[i] = G[i] * G[i];

    #pragma unroll 4
    for (int t = 0; t < SEQ; ++t) {
        float a = 0.f, bt = 0.f;
        #pragma unroll
        for (int bb = 0; bb < NB; ++bb) {
            a  = fmaf(us[t * NB + bb], G2[bb], a);
            bt = fmaf(vs[t * NB + bb], G[bb], bt);
        }
        const float ht = h[t];
        out[(long)t * VOCAB + v] = fmaf(ht, bt, fmaf(ht * ht, Cs[t], a));
    }
}

extern "C" void kernel_launch(void* const* d_in, const int* in_sizes, int n_in,
                              void* d_out, int out_size, void* d_ws, size_t ws_size,
                              hipStream_t stream) {
    const int*   tokens  = (const int*)d_in[0];
    const float* E       = (const float*)d_in[1];
    const float* bubbles = (const float*)d_in[2];
    const float* mdb     = (const float*)d_in[3];
    const float* ns      = (const float*)d_in[4];
    float* out = (float*)d_out;
    float* ws  = (float*)d_ws;

    hipLaunchKernelGGL(foam_scan_kernel, dim3(1), dim3(64), 0, stream,
                       tokens, E, bubbles, mdb, ns, ws);
    hipLaunchKernelGGL(foam_logits_kernel, dim3(VOCAB / 128), dim3(128), 0, stream,
                       E, bubbles, ws, out);
}

// Round 2
// 370.051 us; speedup vs baseline: 1.4344x; 1.4344x over previous
//
#include <hip/hip_runtime.h>
#include <math.h>

#define VOCAB 32000
#define D 256
#define NB 32
#define NEQ 5
#define SEQ 64
#define NBASIS 96   // 32 bubbles + 64 token vectors

// ws layout (float offsets)
#define WS_S     0                          // [96][96] Gram of basis U=[B;X]
#define WS_COEF  (NBASIS*NBASIS)            // [SEQ][96] x_wm coefficients
#define WS_U     (WS_COEF + SEQ*NBASIS)     // [SEQ][NB]
#define WS_VV    (WS_U + SEQ*NB)            // [SEQ][NB]
#define WS_C     (WS_VV + SEQ*NB)           // [SEQ]
#define WS_XWM   (WS_C + SEQ)               // [SEQ][D]

// ---------------------------------------------------------------------------
// K1: Gram matrix S[i][j] = u_i . u_j, basis u_i = (i<32 ? bubbles_i : E[tok_{i-32}])
// 36 blocks x 256 threads, one dot(256) per thread.
// ---------------------------------------------------------------------------
__global__ __launch_bounds__(256) void foam_grams(
    const int* __restrict__ tokens, const float* __restrict__ E,
    const float* __restrict__ bubbles, float* __restrict__ ws)
{
    const int idx = blockIdx.x * 256 + threadIdx.x;   // < 9216
    const int i = idx / NBASIS, j = idx % NBASIS;
    const float4* ra = (const float4*)((i < NB) ? (bubbles + i * D)
                                                : (E + (long)tokens[i - NB] * D));
    const float4* rb = (const float4*)((j < NB) ? (bubbles + j * D)
                                                : (E + (long)tokens[j - NB] * D));
    float a0 = 0.f, a1 = 0.f, a2 = 0.f, a3 = 0.f;
    #pragma unroll
    for (int k = 0; k < D / 4; k += 4) {
        float4 x, y;
        x = ra[k];     y = rb[k];
        a0 = fmaf(x.x, y.x, fmaf(x.y, y.y, fmaf(x.z, y.z, fmaf(x.w, y.w, a0))));
        x = ra[k + 1]; y = rb[k + 1];
        a1 = fmaf(x.x, y.x, fmaf(x.y, y.y, fmaf(x.z, y.z, fmaf(x.w, y.w, a1))));
        x = ra[k + 2]; y = rb[k + 2];
        a2 = fmaf(x.x, y.x, fmaf(x.y, y.y, fmaf(x.z, y.z, fmaf(x.w, y.w, a2))));
        x = ra[k + 3]; y = rb[k + 3];
        a3 = fmaf(x.x, y.x, fmaf(x.y, y.y, fmaf(x.z, y.z, fmaf(x.w, y.w, a3))));
    }
    ws[WS_S + i * NBASIS + j] = (a0 + a1) + (a2 + a3);
}

// ---------------------------------------------------------------------------
// K2: sequential scan, single wave, pure scalar coefficient math.
// State: m[96] (mm coefficients over basis), mm2 = |mm|^2.
// Per token: xdm=x.mm, mmb_b=mm.bub_b (96x32 matvec), closed-form foam,
// emits u/vv/C and x_wm coefficients.
// ---------------------------------------------------------------------------
__global__ __launch_bounds__(64) void foam_scan2(
    const float* __restrict__ p_mdb, const float* __restrict__ p_ns,
    float* __restrict__ ws)
{
    const int l = threadIdx.x;
    const int b = l & 31;
    const int half = l >> 5;

    __shared__ float GBT[NBASIS][33];   // GBT[i][b] = S[b][i]  (b<32)
    __shared__ float Gx[SEQ][NBASIS];   // Gx[t][i]  = S[32+t][i]
    __shared__ float m_s[NBASIS];
    __shared__ float als[NB];

    const float* wsS = ws + WS_S;
    for (int e = l; e < NB * NBASIS; e += 64) {
        int bb = e / NBASIS, i = e % NBASIS;
        GBT[i][bb] = wsS[e];
    }
    for (int e = l; e < SEQ * NBASIS; e += 64)
        ((float*)Gx)[e] = wsS[NB * NBASIS + e];
    m_s[l] = 0.f;
    if (l < 32) m_s[64 + l] = 0.f;
    __syncthreads();

    const float mdb  = p_mdb[0];
    const float sens = fabsf(p_ns[0]);
    const float scale = 0.0625f;
    float mm2 = 0.f;

    float* wsCOEF = ws + WS_COEF;
    float* wsU    = ws + WS_U;
    float* wsVV   = ws + WS_VV;
    float* wsC    = ws + WS_C;

    for (int t = 0; t < SEQ; ++t) {
        const float* gx = &Gx[t][0];

        // xdm = x_t . mm  (96-dot, all lanes)
        float xp = gx[l] * m_s[l];
        if (l < 32) xp = fmaf(gx[64 + l], m_s[64 + l], xp);
        #pragma unroll
        for (int off = 32; off; off >>= 1) xp += __shfl_xor(xp, off);
        const float xdm = xp;

        // mmb_b = mm . bub_b : 96x32 matvec, 2 lanes per b
        const int i0 = half * 48;
        float a0 = 0.f, a1 = 0.f, a2 = 0.f, a3 = 0.f;
        #pragma unroll
        for (int ii = 0; ii < 48; ii += 4) {
            a0 = fmaf(GBT[i0 + ii][b],     m_s[i0 + ii],     a0);
            a1 = fmaf(GBT[i0 + ii + 1][b], m_s[i0 + ii + 1], a1);
            a2 = fmaf(GBT[i0 + ii + 2][b], m_s[i0 + ii + 2], a2);
            a3 = fmaf(GBT[i0 + ii + 3][b], m_s[i0 + ii + 3], a3);
        }
        float mp = (a0 + a1) + (a2 + a3);
        const float mmb = mp + __shfl_xor(mp, 32);

        const float bxt = gx[b];        // bub_b . x_t
        const float px  = gx[32 + t];   // |x_t|^2

        const float mem_norm = sqrtf(mm2) + 1e-10f;
        const float x_norm   = sqrtf(px) + 1e-10f;
        const float nov = (mem_norm > 1e-8f) ? (1.f - xdm / (x_norm * mem_norm)) : 1.f;
        const float decay = 1.f / (1.f + __expf(sens * nov - mdb));
        const float omd = 1.f - decay;

        const float q = px + 2.f * decay * xdm + decay * decay * mm2;
        const float c = bxt + decay * mmb;

        // closed-form equilibrium (values tiny: skip max-subtract)
        float alpha = 1.f, w = 0.f;
        #pragma unroll
        for (int k = 0; k <= NEQ; ++k) {
            float dv = (alpha * c + (1.f - alpha) * q) * scale;
            float ev = __expf(dv);
            float sm = ev;
            #pragma unroll
            for (int off = 16; off; off >>= 1) sm += __shfl_xor(sm, off);
            w = ev / sm;
            if (k < NEQ) alpha *= (1.f - w);
        }
        const float p = w;

        const float bn2 = GBT[b][b];
        const float oma = 1.f - alpha;
        const float s2 = alpha * alpha * bn2 + 2.f * alpha * oma * c + oma * oma * q;
        const float nrm = sqrtf(s2) + 1e-10f;
        const float g = p / (nrm * nrm);

        if (half == 0) wsU[t * NB + b]  = g * alpha * alpha;
        else           wsVV[t * NB + b] = 2.f * g * alpha * oma;
        float Cp = g * oma * oma;
        #pragma unroll
        for (int off = 16; off; off >>= 1) Cp += __shfl_xor(Cp, off);
        if (l == 0) wsC[t] = Cp;

        // x_wm_t coefficients (uses OLD m): decay*m + e_t
        wsCOEF[t * NBASIS + l] = decay * m_s[l] + ((l == 32 + t) ? 1.f : 0.f);
        if (l < 32)
            wsCOEF[t * NBASIS + 64 + l] = decay * m_s[64 + l] + ((64 + l == 32 + t) ? 1.f : 0.f);

        if (half == 0) als[b] = alpha;
        __syncthreads();

        // (GBB.alpha)_b for |u1|^2
        const int b0 = half * 16;
        float ga = 0.f;
        #pragma unroll
        for (int jj = 0; jj < 16; ++jj)
            ga = fmaf(GBT[b0 + jj][b], als[b0 + jj], ga);
        ga += __shfl_xor(ga, 32);

        // fused reductions over 32 bubbles (each half complete)
        float r0 = alpha, r1 = alpha * c, r2 = alpha * mmb, r3 = alpha * ga;
        #pragma unroll
        for (int off = 16; off; off >>= 1) {
            r0 += __shfl_xor(r0, off);
            r1 += __shfl_xor(r1, off);
            r2 += __shfl_xor(r2, off);
            r3 += __shfl_xor(r3, off);
        }

        const float msc = (32.f - r0) * (1.f / 32.f);
        const float k1 = decay * (1.f + omd * msc);
        const float mmxwm = xdm + decay * mm2;
        const float mmms = r2 * (1.f / 32.f) + msc * mmxwm;
        const float u1sq = r3 * (1.f / 1024.f);
        const float msms = u1sq + 2.f * msc * (r1 * (1.f / 32.f)) + msc * msc * q;
        mm2 = decay * decay * mm2 + 2.f * decay * omd * mmms + omd * omd * msms;

        // m update
        const float addb = (l < 32) ? omd * alpha * (1.f / 32.f) : 0.f;
        float nm = k1 * m_s[l] + addb + ((l == 32 + t) ? omd * msc : 0.f);
        float nm2 = 0.f;
        if (l < 32) nm2 = k1 * m_s[64 + l] + ((64 + l == 32 + t) ? omd * msc : 0.f);
        __syncthreads();   // all reads of old m done
        m_s[l] = nm;
        if (l < 32) m_s[64 + l] = nm2;
        __syncthreads();
    }
}

// ---------------------------------------------------------------------------
// K3: reconstruct x_wm[t][d] = sum_i coef[t][i] * u_i[d].  64 blocks x 256 thr.
// ---------------------------------------------------------------------------
__global__ __launch_bounds__(256) void foam_recon(
    const int* __restrict__ tokens, const float* __restrict__ E,
    const float* __restrict__ bubbles, float* __restrict__ ws)
{
    const int t = blockIdx.x;
    const int d = threadIdx.x;
    __shared__ float cf[NBASIS];
    __shared__ int stok[SEQ];
    if (d < NBASIS) cf[d] = ws[WS_COEF + t * NBASIS + d];
    if (d < SEQ) stok[d] = tokens[d];
    __syncthreads();
    float acc = 0.f;
    #pragma unroll 8
    for (int bb = 0; bb < NB; ++bb) acc = fmaf(cf[bb], bubbles[bb * D + d], acc);
    #pragma unroll 8
    for (int j = 0; j < SEQ; ++j) acc = fmaf(cf[32 + j], E[(long)stok[j] * D + d], acc);
    ws[WS_XWM + t * D + d] = acc;
}

// ---------------------------------------------------------------------------
// K4: logits[t][v] = A + h*B + h^2*C.  One thread per vocab row.
// Epilogue FULLY unrolled so h[] stays in VGPRs (no scratch).
// ---------------------------------------------------------------------------
__global__ __launch_bounds__(128) void foam_logits(
    const float* __restrict__ E,
    const float* __restrict__ bubbles,
    const float* __restrict__ ws,
    float* __restrict__ out)
{
    __shared__ __align__(16) float bub[NB * D];    // 32 KB
    __shared__ __align__(16) float xwm[SEQ * D];   // 64 KB
    __shared__ __align__(16) float us[SEQ * NB];   // 8 KB
    __shared__ __align__(16) float vs[SEQ * NB];   // 8 KB
    __shared__ float Cs[SEQ];

    const int tid = threadIdx.x;
    for (int i = tid; i < NB * D / 4; i += 128)   ((float4*)bub)[i] = ((const float4*)bubbles)[i];
    for (int i = tid; i < SEQ * D / 4; i += 128)  ((float4*)xwm)[i] = ((const float4*)(ws + WS_XWM))[i];
    for (int i = tid; i < SEQ * NB / 4; i += 128) ((float4*)us)[i] = ((const float4*)(ws + WS_U))[i];
    for (int i = tid; i < SEQ * NB / 4; i += 128) ((float4*)vs)[i] = ((const float4*)(ws + WS_VV))[i];
    if (tid < SEQ) Cs[tid] = (ws + WS_C)[tid];
    __syncthreads();

    const int v = blockIdx.x * 128 + tid;
    const float4* erow = (const float4*)(E + (long)v * D);

    float G[NB];
    float h[SEQ];
    #pragma unroll
    for (int i = 0; i < NB; ++i) G[i] = 0.f;
    #pragma unroll
    for (int i = 0; i < SEQ; ++i) h[i] = 0.f;

    for (int dc = 0; dc < D / 4; ++dc) {
        const float4 e = erow[dc];
        #pragma unroll
        for (int bb = 0; bb < NB; ++bb) {
            float4 bv = ((const float4*)bub)[bb * (D / 4) + dc];
            G[bb] = fmaf(e.x, bv.x, fmaf(e.y, bv.y, fmaf(e.z, bv.z, fmaf(e.w, bv.w, G[bb]))));
        }
        #pragma unroll
        for (int t = 0; t < SEQ; ++t) {
            float4 xv = ((const float4*)xwm)[t * (D / 4) + dc];
            h[t] = fmaf(e.x, xv.x, fmaf(e.y, xv.y, fmaf(e.z, xv.z, fmaf(e.w, xv.w, h[t]))));
        }
    }

    float G2[NB];
    #pragma unroll
    for (int i = 0; i < NB; ++i) G2[i] = G[i] * G[i];

    #pragma unroll
    for (int t = 0; t < SEQ; ++t) {
        float a = 0.f, bt = 0.f;
        #pragma unroll
        for (int bb = 0; bb < NB; ++bb) {
            a  = fmaf(us[t * NB + bb], G2[bb], a);
            bt = fmaf(vs[t * NB + bb], G[bb], bt);
        }
        const float ht = h[t];
        out[(long)t * VOCAB + v] = fmaf(ht, bt, fmaf(ht * ht, Cs[t], a));
    }
}

extern "C" void kernel_launch(void* const* d_in, const int* in_sizes, int n_in,
                              void* d_out, int out_size, void* d_ws, size_t ws_size,
                              hipStream_t stream) {
    const int*   tokens  = (const int*)d_in[0];
    const float* E       = (const float*)d_in[1];
    const float* bubbles = (const float*)d_in[2];
    const float* mdb     = (const float*)d_in[3];
    const float* ns      = (const float*)d_in[4];
    float* out = (float*)d_out;
    float* ws  = (float*)d_ws;

    hipLaunchKernelGGL(foam_grams, dim3((NBASIS * NBASIS) / 256), dim3(256), 0, stream,
                       tokens, E, bubbles, ws);
    hipLaunchKernelGGL(foam_scan2, dim3(1), dim3(64), 0, stream, mdb, ns, ws);
    hipLaunchKernelGGL(foam_recon, dim3(SEQ), dim3(256), 0, stream,
                       tokens, E, bubbles, ws);
    hipLaunchKernelGGL(foam_logits, dim3(VOCAB / 128), dim3(128), 0, stream,
                       E, bubbles, ws, out);
}

// Round 3
// 216.402 us; speedup vs baseline: 2.4529x; 1.7100x over previous
//
#include <hip/hip_runtime.h>
#include <math.h>

#define VOCAB 32000
#define D 256
#define NB 32
#define NEQ 5
#define SEQ 64
#define NBASIS 96   // 32 bubbles + 64 token vectors

// ws layout (float offsets)
#define WS_S     0                          // [96][96] Gram of basis U=[B;X]
#define WS_COEF  (NBASIS*NBASIS)            // [SEQ][96] x_wm coefficients
#define WS_U     (WS_COEF + SEQ*NBASIS)     // [SEQ][NB]
#define WS_VV    (WS_U + SEQ*NB)            // [SEQ][NB]
#define WS_C     (WS_VV + SEQ*NB)           // [SEQ]
#define WS_XWM   (WS_C + SEQ)               // [SEQ][D]

typedef __attribute__((ext_vector_type(8))) short short8v;
typedef __attribute__((ext_vector_type(4))) float f32x4;

// ---------------------------------------------------------------------------
// K1: Gram matrix S[i][j] = u_i . u_j
// ---------------------------------------------------------------------------
__global__ __launch_bounds__(256) void foam_grams(
    const int* __restrict__ tokens, const float* __restrict__ E,
    const float* __restrict__ bubbles, float* __restrict__ ws)
{
    const int idx = blockIdx.x * 256 + threadIdx.x;   // < 9216
    const int i = idx / NBASIS, j = idx % NBASIS;
    const float4* ra = (const float4*)((i < NB) ? (bubbles + i * D)
                                                : (E + (long)tokens[i - NB] * D));
    const float4* rb = (const float4*)((j < NB) ? (bubbles + j * D)
                                                : (E + (long)tokens[j - NB] * D));
    float a0 = 0.f, a1 = 0.f, a2 = 0.f, a3 = 0.f;
    #pragma unroll
    for (int k = 0; k < D / 4; k += 4) {
        float4 x, y;
        x = ra[k];     y = rb[k];
        a0 = fmaf(x.x, y.x, fmaf(x.y, y.y, fmaf(x.z, y.z, fmaf(x.w, y.w, a0))));
        x = ra[k + 1]; y = rb[k + 1];
        a1 = fmaf(x.x, y.x, fmaf(x.y, y.y, fmaf(x.z, y.z, fmaf(x.w, y.w, a1))));
        x = ra[k + 2]; y = rb[k + 2];
        a2 = fmaf(x.x, y.x, fmaf(x.y, y.y, fmaf(x.z, y.z, fmaf(x.w, y.w, a2))));
        x = ra[k + 3]; y = rb[k + 3];
        a3 = fmaf(x.x, y.x, fmaf(x.y, y.y, fmaf(x.z, y.z, fmaf(x.w, y.w, a3))));
    }
    ws[WS_S + i * NBASIS + j] = (a0 + a1) + (a2 + a3);
}

// ---------------------------------------------------------------------------
// K2: sequential scan in Gram-coefficient space (unchanged, verified).
// ---------------------------------------------------------------------------
__global__ __launch_bounds__(64) void foam_scan2(
    const float* __restrict__ p_mdb, const float* __restrict__ p_ns,
    float* __restrict__ ws)
{
    const int l = threadIdx.x;
    const int b = l & 31;
    const int half = l >> 5;

    __shared__ float GBT[NBASIS][33];
    __shared__ float Gx[SEQ][NBASIS];
    __shared__ float m_s[NBASIS];
    __shared__ float als[NB];

    const float* wsS = ws + WS_S;
    for (int e = l; e < NB * NBASIS; e += 64) {
        int bb = e / NBASIS, i = e % NBASIS;
        GBT[i][bb] = wsS[e];
    }
    for (int e = l; e < SEQ * NBASIS; e += 64)
        ((float*)Gx)[e] = wsS[NB * NBASIS + e];
    m_s[l] = 0.f;
    if (l < 32) m_s[64 + l] = 0.f;
    __syncthreads();

    const float mdb  = p_mdb[0];
    const float sens = fabsf(p_ns[0]);
    const float scale = 0.0625f;
    float mm2 = 0.f;

    float* wsCOEF = ws + WS_COEF;
    float* wsU    = ws + WS_U;
    float* wsVV   = ws + WS_VV;
    float* wsC    = ws + WS_C;

    for (int t = 0; t < SEQ; ++t) {
        const float* gx = &Gx[t][0];

        float xp = gx[l] * m_s[l];
        if (l < 32) xp = fmaf(gx[64 + l], m_s[64 + l], xp);
        #pragma unroll
        for (int off = 32; off; off >>= 1) xp += __shfl_xor(xp, off);
        const float xdm = xp;

        const int i0 = half * 48;
        float a0 = 0.f, a1 = 0.f, a2 = 0.f, a3 = 0.f;
        #pragma unroll
        for (int ii = 0; ii < 48; ii += 4) {
            a0 = fmaf(GBT[i0 + ii][b],     m_s[i0 + ii],     a0);
            a1 = fmaf(GBT[i0 + ii + 1][b], m_s[i0 + ii + 1], a1);
            a2 = fmaf(GBT[i0 + ii + 2][b], m_s[i0 + ii + 2], a2);
            a3 = fmaf(GBT[i0 + ii + 3][b], m_s[i0 + ii + 3], a3);
        }
        float mp = (a0 + a1) + (a2 + a3);
        const float mmb = mp + __shfl_xor(mp, 32);

        const float bxt = gx[b];
        const float px  = gx[32 + t];

        const float mem_norm = sqrtf(mm2) + 1e-10f;
        const float x_norm   = sqrtf(px) + 1e-10f;
        const float nov = (mem_norm > 1e-8f) ? (1.f - xdm / (x_norm * mem_norm)) : 1.f;
        const float decay = 1.f / (1.f + __expf(sens * nov - mdb));
        const float omd = 1.f - decay;

        const float q = px + 2.f * decay * xdm + decay * decay * mm2;
        const float c = bxt + decay * mmb;

        float alpha = 1.f, w = 0.f;
        #pragma unroll
        for (int k = 0; k <= NEQ; ++k) {
            float dv = (alpha * c + (1.f - alpha) * q) * scale;
            float ev = __expf(dv);
            float sm = ev;
            #pragma unroll
            for (int off = 16; off; off >>= 1) sm += __shfl_xor(sm, off);
            w = ev / sm;
            if (k < NEQ) alpha *= (1.f - w);
        }
        const float p = w;

        const float bn2 = GBT[b][b];
        const float oma = 1.f - alpha;
        const float s2 = alpha * alpha * bn2 + 2.f * alpha * oma * c + oma * oma * q;
        const float nrm = sqrtf(s2) + 1e-10f;
        const float g = p / (nrm * nrm);

        if (half == 0) wsU[t * NB + b]  = g * alpha * alpha;
        else           wsVV[t * NB + b] = 2.f * g * alpha * oma;
        float Cp = g * oma * oma;
        #pragma unroll
        for (int off = 16; off; off >>= 1) Cp += __shfl_xor(Cp, off);
        if (l == 0) wsC[t] = Cp;

        wsCOEF[t * NBASIS + l] = decay * m_s[l] + ((l == 32 + t) ? 1.f : 0.f);
        if (l < 32)
            wsCOEF[t * NBASIS + 64 + l] = decay * m_s[64 + l] + ((64 + l == 32 + t) ? 1.f : 0.f);

        if (half == 0) als[b] = alpha;
        __syncthreads();

        const int b0 = half * 16;
        float ga = 0.f;
        #pragma unroll
        for (int jj = 0; jj < 16; ++jj)
            ga = fmaf(GBT[b0 + jj][b], als[b0 + jj], ga);
        ga += __shfl_xor(ga, 32);

        float r0 = alpha, r1 = alpha * c, r2 = alpha * mmb, r3 = alpha * ga;
        #pragma unroll
        for (int off = 16; off; off >>= 1) {
            r0 += __shfl_xor(r0, off);
            r1 += __shfl_xor(r1, off);
            r2 += __shfl_xor(r2, off);
            r3 += __shfl_xor(r3, off);
        }

        const float msc = (32.f - r0) * (1.f / 32.f);
        const float k1 = decay * (1.f + omd * msc);
        const float mmxwm = xdm + decay * mm2;
        const float mmms = r2 * (1.f / 32.f) + msc * mmxwm;
        const float u1sq = r3 * (1.f / 1024.f);
        const float msms = u1sq + 2.f * msc * (r1 * (1.f / 32.f)) + msc * msc * q;
        mm2 = decay * decay * mm2 + 2.f * decay * omd * mmms + omd * omd * msms;

        const float addb = (l < 32) ? omd * alpha * (1.f / 32.f) : 0.f;
        float nm = k1 * m_s[l] + addb + ((l == 32 + t) ? omd * msc : 0.f);
        float nm2 = 0.f;
        if (l < 32) nm2 = k1 * m_s[64 + l] + ((64 + l == 32 + t) ? omd * msc : 0.f);
        __syncthreads();
        m_s[l] = nm;
        if (l < 32) m_s[64 + l] = nm2;
        __syncthreads();
    }
}

// ---------------------------------------------------------------------------
// K3: reconstruct x_wm[t][d] (f32, feeds the MFMA B-operand rows 32..95)
// ---------------------------------------------------------------------------
__global__ __launch_bounds__(256) void foam_recon(
    const int* __restrict__ tokens, const float* __restrict__ E,
    const float* __restrict__ bubbles, float* __restrict__ ws)
{
    const int t = blockIdx.x;
    const int d = threadIdx.x;
    __shared__ float cf[NBASIS];
    __shared__ int stok[SEQ];
    if (d < NBASIS) cf[d] = ws[WS_COEF + t * NBASIS + d];
    if (d < SEQ) stok[d] = tokens[d];
    __syncthreads();
    float acc = 0.f;
    #pragma unroll 8
    for (int bb = 0; bb < NB; ++bb) acc = fmaf(cf[bb], bubbles[bb * D + d], acc);
    #pragma unroll 8
    for (int j = 0; j < SEQ; ++j) acc = fmaf(cf[32 + j], E[(long)stok[j] * D + d], acc);
    ws[WS_XWM + t * D + d] = acc;
}

// ---------------------------------------------------------------------------
// K4: MFMA split-bf16 GEMM H = E @ [bub; xwm]^T + fused Born-rule epilogue.
// 1000 blocks x 512 thr; waves 0..5 own one 16-basis N-tile each (B-frags in
// VGPRs, loaded once); 2 M-tiles of 16 rows per block.
// Split-bf16: x = hi + lo, 3 MFMAs (hi*hi + hi*lo + lo*hi), rel err ~2^-16.
// ---------------------------------------------------------------------------
#define MROWS 32
#define HS 100   // H_lds row stride (400 B: 16B-aligned, rows 2-way banked)
#define US 36    // us/vs row stride (conflict-free across 4 t-groups)

__device__ __forceinline__ void split_bf16(const float* p, short8v& hi, short8v& lo) {
    float4 f0 = *(const float4*)p;
    float4 f1 = *(const float4*)(p + 4);
    float f[8] = {f0.x, f0.y, f0.z, f0.w, f1.x, f1.y, f1.z, f1.w};
    #pragma unroll
    for (int j = 0; j < 8; ++j) {
        unsigned xb = __builtin_bit_cast(unsigned, f[j]);
        unsigned hb = xb & 0xFFFF0000u;
        float fl = f[j] - __builtin_bit_cast(float, hb);
        unsigned lb = __builtin_bit_cast(unsigned, fl);
        hi[j] = (short)(hb >> 16);
        lo[j] = (short)(lb >> 16);
    }
}

__global__ __launch_bounds__(512, 4) void foam_mfma_logits(
    const float* __restrict__ E,
    const float* __restrict__ bubbles,
    const float* __restrict__ ws,
    float* __restrict__ out)
{
    __shared__ float H[MROWS][HS];        // 12.8 KB
    __shared__ float us[SEQ * US];        // 9.2 KB
    __shared__ float vs[SEQ * US];        // 9.2 KB
    __shared__ float Cs[SEQ];

    const int tid = threadIdx.x;
    const int w = tid >> 6;      // wave 0..7
    const int l = tid & 63;
    const int lm = l & 15;
    const int lq = l >> 4;       // quarter 0..3

    // stage us/vs (re-strided) + Cs
    for (int i = tid; i < SEQ * NB; i += 512) {
        int t = i >> 5, bb = i & 31;
        us[t * US + bb] = ws[WS_U + i];
        vs[t * US + bb] = ws[WS_VV + i];
    }
    if (tid < SEQ) Cs[tid] = ws[WS_C + tid];

    const long vb = (long)blockIdx.x * MROWS;

    if (w < 6) {
        // B-fragments: 16 basis rows for this wave, all 8 K-steps, hi+lo.
        short8v bhi[8], blo[8];
        const int n = w * 16 + lm;
        const float* wrow = (w < 2) ? (bubbles + n * D)
                                    : (ws + WS_XWM + (n - 32) * D);
        #pragma unroll
        for (int ks = 0; ks < 8; ++ks)
            split_bf16(wrow + ks * 32 + lq * 8, bhi[ks], blo[ks]);

        #pragma unroll
        for (int mt = 0; mt < 2; ++mt) {
            f32x4 acc = {0.f, 0.f, 0.f, 0.f};
            const float* arow = E + (vb + mt * 16 + lm) * D + lq * 8;
            #pragma unroll
            for (int ks = 0; ks < 8; ++ks) {
                short8v ahi, alo;
                split_bf16(arow + ks * 32, ahi, alo);
                acc = __builtin_amdgcn_mfma_f32_16x16x32_bf16(ahi, bhi[ks], acc, 0, 0, 0);
                acc = __builtin_amdgcn_mfma_f32_16x16x32_bf16(ahi, blo[ks], acc, 0, 0, 0);
                acc = __builtin_amdgcn_mfma_f32_16x16x32_bf16(alo, bhi[ks], acc, 0, 0, 0);
            }
            // D layout: col = l&15 (basis), row = (l>>4)*4 + r  [m89-verified]
            #pragma unroll
            for (int r = 0; r < 4; ++r)
                H[mt * 16 + lq * 4 + r][w * 16 + lm] = acc[r];
        }
    }
    __syncthreads();

    // Epilogue: thread covers rows {lm, 16+lm} x tokens {w*8+lq, w*8+lq+4}
    const int t0 = w * 8 + lq;
    const int t1 = t0 + 4;
    const float c0 = Cs[t0], c1 = Cs[t1];

    #pragma unroll
    for (int mt = 0; mt < 2; ++mt) {
        const int row = mt * 16 + lm;
        float G[NB], G2[NB];
        #pragma unroll
        for (int i = 0; i < 8; ++i)
            *(float4*)&G[4 * i] = *(const float4*)&H[row][4 * i];
        #pragma unroll
        for (int i = 0; i < NB; ++i) G2[i] = G[i] * G[i];

        float a0 = 0.f, b0 = 0.f, a1 = 0.f, b1 = 0.f;
        #pragma unroll
        for (int i = 0; i < 8; ++i) {
            float4 u0 = *(const float4*)&us[t0 * US + 4 * i];
            float4 v0 = *(const float4*)&vs[t0 * US + 4 * i];
            float4 u1 = *(const float4*)&us[t1 * US + 4 * i];
            float4 v1 = *(const float4*)&vs[t1 * US + 4 * i];
            a0 = fmaf(u0.x, G2[4*i], fmaf(u0.y, G2[4*i+1], fmaf(u0.z, G2[4*i+2], fmaf(u0.w, G2[4*i+3], a0))));
            b0 = fmaf(v0.x, G[4*i],  fmaf(v0.y, G[4*i+1],  fmaf(v0.z, G[4*i+2],  fmaf(v0.w, G[4*i+3],  b0))));
            a1 = fmaf(u1.x, G2[4*i], fmaf(u1.y, G2[4*i+1], fmaf(u1.z, G2[4*i+2], fmaf(u1.w, G2[4*i+3], a1))));
            b1 = fmaf(v1.x, G[4*i],  fmaf(v1.y, G[4*i+1],  fmaf(v1.z, G[4*i+2],  fmaf(v1.w, G[4*i+3],  b1))));
        }
        const float h0 = H[row][32 + t0];
        const float h1 = H[row][32 + t1];
        out[(long)t0 * VOCAB + vb + row] = fmaf(h0, b0, fmaf(h0 * h0, c0, a0));
        out[(long)t1 * VOCAB + vb + row] = fmaf(h1, b1, fmaf(h1 * h1, c1, a1));
    }
}

extern "C" void kernel_launch(void* const* d_in, const int* in_sizes, int n_in,
                              void* d_out, int out_size, void* d_ws, size_t ws_size,
                              hipStream_t stream) {
    const int*   tokens  = (const int*)d_in[0];
    const float* E       = (const float*)d_in[1];
    const float* bubbles = (const float*)d_in[2];
    const float* mdb     = (const float*)d_in[3];
    const float* ns      = (const float*)d_in[4];
    float* out = (float*)d_out;
    float* ws  = (float*)d_ws;

    hipLaunchKernelGGL(foam_grams, dim3((NBASIS * NBASIS) / 256), dim3(256), 0, stream,
                       tokens, E, bubbles, ws);
    hipLaunchKernelGGL(foam_scan2, dim3(1), dim3(64), 0, stream, mdb, ns, ws);
    hipLaunchKernelGGL(foam_recon, dim3(SEQ), dim3(256), 0, stream,
                       tokens, E, bubbles, ws);
    hipLaunchKernelGGL(foam_mfma_logits, dim3(VOCAB / MROWS), dim3(512), 0, stream,
                       E, bubbles, ws, out);
}

// Round 5
// 140.203 us; speedup vs baseline: 3.7860x; 1.5435x over previous
//
#include <hip/hip_runtime.h>
#include <math.h>

#define VOCAB 32000
#define D 256
#define NB 32
#define NEQ 5
#define SEQ 64
#define NBASIS 96   // 32 bubbles + 64 token vectors

// ws layout (float offsets)
#define WS_S     0                          // [96][96] Gram of basis U=[B;X]
#define WS_COEF  (NBASIS*NBASIS)            // [SEQ][96] x_wm coefficients
#define WS_U     (WS_COEF + SEQ*NBASIS)     // [SEQ][NB]
#define WS_VV    (WS_U + SEQ*NB)            // [SEQ][NB]
#define WS_C     (WS_VV + SEQ*NB)           // [SEQ]
#define WS_XWM   (WS_C + SEQ)               // [SEQ][D]

typedef __attribute__((ext_vector_type(8))) short short8v;
typedef __attribute__((ext_vector_type(4))) float f32x4;

// ---------------------------------------------------------------------------
// K1: Gram matrix S[i][j] = u_i . u_j
// ---------------------------------------------------------------------------
__global__ __launch_bounds__(256) void foam_grams(
    const int* __restrict__ tokens, const float* __restrict__ E,
    const float* __restrict__ bubbles, float* __restrict__ ws)
{
    const int idx = blockIdx.x * 256 + threadIdx.x;   // < 9216
    const int i = idx / NBASIS, j = idx % NBASIS;
    const float4* ra = (const float4*)((i < NB) ? (bubbles + i * D)
                                                : (E + (long)tokens[i - NB] * D));
    const float4* rb = (const float4*)((j < NB) ? (bubbles + j * D)
                                                : (E + (long)tokens[j - NB] * D));
    float a0 = 0.f, a1 = 0.f, a2 = 0.f, a3 = 0.f;
    #pragma unroll
    for (int k = 0; k < D / 4; k += 4) {
        float4 x, y;
        x = ra[k];     y = rb[k];
        a0 = fmaf(x.x, y.x, fmaf(x.y, y.y, fmaf(x.z, y.z, fmaf(x.w, y.w, a0))));
        x = ra[k + 1]; y = rb[k + 1];
        a1 = fmaf(x.x, y.x, fmaf(x.y, y.y, fmaf(x.z, y.z, fmaf(x.w, y.w, a1))));
        x = ra[k + 2]; y = rb[k + 2];
        a2 = fmaf(x.x, y.x, fmaf(x.y, y.y, fmaf(x.z, y.z, fmaf(x.w, y.w, a2))));
        x = ra[k + 3]; y = rb[k + 3];
        a3 = fmaf(x.x, y.x, fmaf(x.y, y.y, fmaf(x.z, y.z, fmaf(x.w, y.w, a3))));
    }
    ws[WS_S + i * NBASIS + j] = (a0 + a1) + (a2 + a3);
}

// ---------------------------------------------------------------------------
// Fast cross-lane primitives (single-wave scan). DPP ctrl must be an
// immediate -> template parameter.
// ---------------------------------------------------------------------------
template <int CTRL>
__device__ __forceinline__ float dpp_add(float x) {
    int yi = __builtin_amdgcn_update_dpp(0, __float_as_int(x), CTRL, 0xF, 0xF, true);
    return x + __int_as_float(yi);
}
// all-lane sum over each 32-lane group: xor1,xor2 (quad_perm), ror4, ror8, xor16
__device__ __forceinline__ float sum32(float x) {
    x = dpp_add<0xB1>(x);    // quad_perm [1,0,3,2]  == xor 1
    x = dpp_add<0x4E>(x);    // quad_perm [2,3,0,1]  == xor 2
    x = dpp_add<0x124>(x);   // row_ror:4
    x = dpp_add<0x128>(x);   // row_ror:8
    int yi = __builtin_amdgcn_ds_swizzle(__float_as_int(x), 0x401F);  // xor 16
    return x + __int_as_float(yi);
}
__device__ __forceinline__ float rdlane(float v, int lane) {
    return __int_as_float(__builtin_amdgcn_readlane(__float_as_int(v), lane));
}

// ---------------------------------------------------------------------------
// K2: sequential scan, single wave, register-resident state.
// Incremental functionals: z_l = x_l . mm  (token layout, all 64 lanes)
//                          y_l = bub_{l&31} . mm  (bubble layout, duplicated)
// m coefficients kept per-lane in 2 registers; no LDS writes in the loop.
// ---------------------------------------------------------------------------
__global__ __launch_bounds__(64) void foam_scan3(
    const float* __restrict__ p_mdb, const float* __restrict__ p_ns,
    float* __restrict__ ws)
{
    const int l = threadIdx.x;
    const int b = l & 31;

    __shared__ float S2[SEQ][NBASIS];   // S2[t][i] = S[32+t][i]  (24.5 KB)

    const float* wsS = ws + WS_S;
    // LDS fill: rows 32..95 of the Gram (vectorized)
    for (int e = l; e < SEQ * NBASIS / 4; e += 64)
        ((float4*)S2)[e] = ((const float4*)(wsS + NB * NBASIS))[e];

    // constant per-lane rows of the Gram (registers, unroll-indexed only)
    float gbb_row[NB];   // S[b][j], j<32
    float gxb_row[NB];   // S[32+l][j], j<32
    {
        const float4* pa = (const float4*)(wsS + b * NBASIS);
        const float4* pb = (const float4*)(wsS + (NB + l) * NBASIS);
        #pragma unroll
        for (int i = 0; i < 8; ++i) {
            float4 va = pa[i], vb = pb[i];
            gbb_row[4*i] = va.x; gbb_row[4*i+1] = va.y; gbb_row[4*i+2] = va.z; gbb_row[4*i+3] = va.w;
            gxb_row[4*i] = vb.x; gxb_row[4*i+1] = vb.y; gxb_row[4*i+2] = vb.z; gxb_row[4*i+3] = vb.w;
        }
    }
    const float diag = wsS[(NB + l) * NBASIS + NB + l];   // |x_l|^2
    const float bn2  = wsS[b * NBASIS + b];               // |bub_b|^2

    const float mdb  = p_mdb[0];
    const float sens = fabsf(p_ns[0]);
    const float scale = 0.0625f;

    __syncthreads();

    float z = 0.f, y = 0.f, mm2 = 0.f;
    float m1 = 0.f, m2 = 0.f;     // m[l], m[64+l] (latter meaningful for l<32)

    float* wsCOEF = ws + WS_COEF;
    float* wsU    = ws + WS_U;
    float* wsVV   = ws + WS_VV;
    float* wsC    = ws + WS_C;

    float gxcol = S2[0][b];        // S[b][32+t]  for t=0
    float xxcol = S2[0][NB + l];   // S[32+l][32+t]

    for (int t = 0; t < SEQ; ++t) {
        // ---- scalars for this token ----
        const float xdm = rdlane(z, t);
        const float px  = rdlane(diag, t);
        const float mem_norm = sqrtf(mm2) + 1e-10f;
        const float x_norm   = sqrtf(px) + 1e-10f;
        const float nov = (mem_norm > 1e-8f) ? (1.f - xdm / (x_norm * mem_norm)) : 1.f;
        const float decay = 1.f / (1.f + __expf(sens * nov - mdb));
        const float omd = 1.f - decay;

        // emit x_wm coefficients (OLD m)
        wsCOEF[t * NBASIS + l] = fmaf(decay, m1, (l == NB + t) ? 1.f : 0.f);
        if (l < NB)
            wsCOEF[t * NBASIS + 64 + l] = fmaf(decay, m2, (64 + l == NB + t) ? 1.f : 0.f);

        const float q = px + 2.f * decay * xdm + decay * decay * mm2;
        const float c = fmaf(decay, y, gxcol);

        // prefetch next token's Gram column (hidden under the rounds)
        const int tn = (t + 1) & (SEQ - 1);
        const float gxn = S2[tn][b];
        const float xxn = S2[tn][NB + l];

        // ---- 6 softmax rounds, closed-form equilibrium ----
        const float cq = (c - q) * scale;
        const float qs = q * scale;
        float alpha = 1.f, w = 0.f;
        #pragma unroll
        for (int k = 0; k <= NEQ; ++k) {
            float dv = fmaf(alpha, cq, qs);
            float ev = __expf(dv);
            float sm = sum32(ev);
            w = ev / sm;
            if (k < NEQ) alpha *= (1.f - w);
        }
        const float p = w;

        // ---- per-bubble outputs ----
        const float oma = 1.f - alpha;
        const float s2v = alpha * alpha * bn2 + 2.f * alpha * oma * c + oma * oma * q;
        const float nrm = sqrtf(s2v) + 1e-10f;
        const float g = p / (nrm * nrm);
        if (l < NB) wsU[t * NB + b]  = g * alpha * alpha;
        else        wsVV[t * NB + b] = 2.f * g * alpha * oma;

        // ---- broadcast alphas to SGPRs ----
        float asg[NB];
        #pragma unroll
        for (int j = 0; j < NB; ++j) asg[j] = rdlane(alpha, j);

        // per-lane Gram-weighted alpha sums (constant rows, unrolled)
        float ga0 = 0.f, ga1 = 0.f, ga2 = 0.f, ga3 = 0.f;
        float da0 = 0.f, da1 = 0.f, da2 = 0.f, da3 = 0.f;
        #pragma unroll
        for (int j = 0; j < NB; j += 4) {
            ga0 = fmaf(gbb_row[j],     asg[j],     ga0);
            ga1 = fmaf(gbb_row[j + 1], asg[j + 1], ga1);
            ga2 = fmaf(gbb_row[j + 2], asg[j + 2], ga2);
            ga3 = fmaf(gbb_row[j + 3], asg[j + 3], ga3);
            da0 = fmaf(gxb_row[j],     asg[j],     da0);
            da1 = fmaf(gxb_row[j + 1], asg[j + 1], da1);
            da2 = fmaf(gxb_row[j + 2], asg[j + 2], da2);
            da3 = fmaf(gxb_row[j + 3], asg[j + 3], da3);
        }
        const float ga  = (ga0 + ga1) + (ga2 + ga3);   // (G_BB . alpha)_b
        const float dar = (da0 + da1) + (da2 + da3);   // (Gx_row . alpha)_l

        // ---- reductions over bubbles ----
        const float r0 = sum32(alpha);
        const float r1 = sum32(alpha * c);
        const float r2 = sum32(alpha * y);
        const float r3 = sum32(alpha * ga);
        const float Cp = sum32(g * oma * oma);
        if (l == 0) wsC[t] = Cp;

        // ---- state update (same algebra as verified scan2) ----
        const float msc = (32.f - r0) * (1.f / 32.f);
        const float k1 = decay * fmaf(omd, msc, 1.f);
        const float mmxwm = fmaf(decay, mm2, xdm);
        const float mmms = fmaf(msc, mmxwm, r2 * (1.f / 32.f));
        const float u1sq = r3 * (1.f / 1024.f);
        const float msms = fmaf(msc * msc, q, fmaf(2.f * msc, r1 * (1.f / 32.f), u1sq));
        mm2 = decay * decay * mm2 + 2.f * decay * omd * mmms + omd * omd * msms;

        z = fmaf(k1, z, omd * fmaf(msc, xxcol, dar * (1.f / 32.f)));
        y = fmaf(k1, y, omd * fmaf(msc, gxcol, ga  * (1.f / 32.f)));

        const float inc1 = (l < NB) ? omd * alpha * (1.f / 32.f)
                                    : ((l == NB + t) ? omd * msc : 0.f);
        m1 = fmaf(k1, m1, inc1);
        m2 = fmaf(k1, m2, (l == t - NB) ? omd * msc : 0.f);   // l<32, t>=32

        gxcol = gxn;
        xxcol = xxn;
    }
}

// ---------------------------------------------------------------------------
// K3: reconstruct x_wm[t][d]
// ---------------------------------------------------------------------------
__global__ __launch_bounds__(256) void foam_recon(
    const int* __restrict__ tokens, const float* __restrict__ E,
    const float* __restrict__ bubbles, float* __restrict__ ws)
{
    const int t = blockIdx.x;
    const int d = threadIdx.x;
    __shared__ float cf[NBASIS];
    __shared__ int stok[SEQ];
    if (d < NBASIS) cf[d] = ws[WS_COEF + t * NBASIS + d];
    if (d < SEQ) stok[d] = tokens[d];
    __syncthreads();
    float acc = 0.f;
    #pragma unroll 8
    for (int bb = 0; bb < NB; ++bb) acc = fmaf(cf[bb], bubbles[bb * D + d], acc);
    #pragma unroll 8
    for (int j = 0; j < SEQ; ++j) acc = fmaf(cf[32 + j], E[(long)stok[j] * D + d], acc);
    ws[WS_XWM + t * D + d] = acc;
}

// ---------------------------------------------------------------------------
// K4: MFMA split-bf16 GEMM H = E @ [bub; xwm]^T + fused Born-rule epilogue.
// ---------------------------------------------------------------------------
#define MROWS 32
#define HS 100
#define US 36

__device__ __forceinline__ void split_bf16(const float* p, short8v& hi, short8v& lo) {
    float4 f0 = *(const float4*)p;
    float4 f1 = *(const float4*)(p + 4);
    float f[8] = {f0.x, f0.y, f0.z, f0.w, f1.x, f1.y, f1.z, f1.w};
    #pragma unroll
    for (int j = 0; j < 8; ++j) {
        unsigned xb = __builtin_bit_cast(unsigned, f[j]);
        unsigned hb = xb & 0xFFFF0000u;
        float fl = f[j] - __builtin_bit_cast(float, hb);
        unsigned lb = __builtin_bit_cast(unsigned, fl);
        hi[j] = (short)(hb >> 16);
        lo[j] = (short)(lb >> 16);
    }
}

__global__ __launch_bounds__(512, 4) void foam_mfma_logits(
    const float* __restrict__ E,
    const float* __restrict__ bubbles,
    const float* __restrict__ ws,
    float* __restrict__ out)
{
    __shared__ float H[MROWS][HS];
    __shared__ float us[SEQ * US];
    __shared__ float vs[SEQ * US];
    __shared__ float Cs[SEQ];

    const int tid = threadIdx.x;
    const int w = tid >> 6;
    const int l = tid & 63;
    const int lm = l & 15;
    const int lq = l >> 4;

    for (int i = tid; i < SEQ * NB; i += 512) {
        int t = i >> 5, bb = i & 31;
        us[t * US + bb] = ws[WS_U + i];
        vs[t * US + bb] = ws[WS_VV + i];
    }
    if (tid < SEQ) Cs[tid] = ws[WS_C + tid];

    const long vb = (long)blockIdx.x * MROWS;

    if (w < 6) {
        short8v bhi[8], blo[8];
        const int n = w * 16 + lm;
        const float* wrow = (w < 2) ? (bubbles + n * D)
                                    : (ws + WS_XWM + (n - 32) * D);
        #pragma unroll
        for (int ks = 0; ks < 8; ++ks)
            split_bf16(wrow + ks * 32 + lq * 8, bhi[ks], blo[ks]);

        #pragma unroll
        for (int mt = 0; mt < 2; ++mt) {
            f32x4 acc = {0.f, 0.f, 0.f, 0.f};
            const float* arow = E + (vb + mt * 16 + lm) * D + lq * 8;
            #pragma unroll
            for (int ks = 0; ks < 8; ++ks) {
                short8v ahi, alo;
                split_bf16(arow + ks * 32, ahi, alo);
                acc = __builtin_amdgcn_mfma_f32_16x16x32_bf16(ahi, bhi[ks], acc, 0, 0, 0);
                acc = __builtin_amdgcn_mfma_f32_16x16x32_bf16(ahi, blo[ks], acc, 0, 0, 0);
                acc = __builtin_amdgcn_mfma_f32_16x16x32_bf16(alo, bhi[ks], acc, 0, 0, 0);
            }
            #pragma unroll
            for (int r = 0; r < 4; ++r)
                H[mt * 16 + lq * 4 + r][w * 16 + lm] = acc[r];
        }
    }
    __syncthreads();

    const int t0 = w * 8 + lq;
    const int t1 = t0 + 4;
    const float c0 = Cs[t0], c1 = Cs[t1];

    #pragma unroll
    for (int mt = 0; mt < 2; ++mt) {
        const int row = mt * 16 + lm;
        float G[NB], G2[NB];
        #pragma unroll
        for (int i = 0; i < 8; ++i)
            *(float4*)&G[4 * i] = *(const float4*)&H[row][4 * i];
        #pragma unroll
        for (int i = 0; i < NB; ++i) G2[i] = G[i] * G[i];

        float a0 = 0.f, b0 = 0.f, a1 = 0.f, b1 = 0.f;
        #pragma unroll
        for (int i = 0; i < 8; ++i) {
            float4 u0 = *(const float4*)&us[t0 * US + 4 * i];
            float4 v0 = *(const float4*)&vs[t0 * US + 4 * i];
            float4 u1 = *(const float4*)&us[t1 * US + 4 * i];
            float4 v1 = *(const float4*)&vs[t1 * US + 4 * i];
            a0 = fmaf(u0.x, G2[4*i], fmaf(u0.y, G2[4*i+1], fmaf(u0.z, G2[4*i+2], fmaf(u0.w, G2[4*i+3], a0))));
            b0 = fmaf(v0.x, G[4*i],  fmaf(v0.y, G[4*i+1],  fmaf(v0.z, G[4*i+2],  fmaf(v0.w, G[4*i+3],  b0))));
            a1 = fmaf(u1.x, G2[4*i], fmaf(u1.y, G2[4*i+1], fmaf(u1.z, G2[4*i+2], fmaf(u1.w, G2[4*i+3], a1))));
            b1 = fmaf(v1.x, G[4*i],  fmaf(v1.y, G[4*i+1],  fmaf(v1.z, G[4*i+2],  fmaf(v1.w, G[4*i+3],  b1))));
        }
        const float h0 = H[row][32 + t0];
        const float h1 = H[row][32 + t1];
        out[(long)t0 * VOCAB + vb + row] = fmaf(h0, b0, fmaf(h0 * h0, c0, a0));
        out[(long)t1 * VOCAB + vb + row] = fmaf(h1, b1, fmaf(h1 * h1, c1, a1));
    }
}

extern "C" void kernel_launch(void* const* d_in, const int* in_sizes, int n_in,
                              void* d_out, int out_size, void* d_ws, size_t ws_size,
                              hipStream_t stream) {
    const int*   tokens  = (const int*)d_in[0];
    const float* E       = (const float*)d_in[1];
    const float* bubbles = (const float*)d_in[2];
    const float* mdb     = (const float*)d_in[3];
    const float* ns      = (const float*)d_in[4];
    float* out = (float*)d_out;
    float* ws  = (float*)d_ws;

    hipLaunchKernelGGL(foam_grams, dim3((NBASIS * NBASIS) / 256), dim3(256), 0, stream,
                       tokens, E, bubbles, ws);
    hipLaunchKernelGGL(foam_scan3, dim3(1), dim3(64), 0, stream, mdb, ns, ws);
    hipLaunchKernelGGL(foam_recon, dim3(SEQ), dim3(256), 0, stream,
                       tokens, E, bubbles, ws);
    hipLaunchKernelGGL(foam_mfma_logits, dim3(VOCAB / MROWS), dim3(512), 0, stream,
                       E, bubbles, ws, out);
}

// Round 6
// 122.048 us; speedup vs baseline: 4.3492x; 1.1488x over previous
//
#include <hip/hip_runtime.h>
#include <math.h>

#define VOCAB 32000
#define D 256
#define NB 32
#define NEQ 5
#define SEQ 64
#define NBASIS 96   // 32 bubbles + 64 token vectors

// ws layout (float offsets)
#define WS_S     0                          // [96][96] Gram of basis U=[B;X]
#define WS_COEF  (NBASIS*NBASIS)            // [SEQ][96] x_wm coefficients
#define WS_U     (WS_COEF + SEQ*NBASIS)     // [SEQ][NB]
#define WS_VV    (WS_U + SEQ*NB)            // [SEQ][NB]
#define WS_C     (WS_VV + SEQ*NB)           // [SEQ]
#define WS_XWM   (WS_C + SEQ)               // [SEQ][D]

typedef __attribute__((ext_vector_type(8))) short short8v;
typedef __attribute__((ext_vector_type(4))) float f32x4;

// ---------------------------------------------------------------------------
// K1: Gram matrix S[i][j] = u_i . u_j
// ---------------------------------------------------------------------------
__global__ __launch_bounds__(256) void foam_grams(
    const int* __restrict__ tokens, const float* __restrict__ E,
    const float* __restrict__ bubbles, float* __restrict__ ws)
{
    const int idx = blockIdx.x * 256 + threadIdx.x;   // < 9216
    const int i = idx / NBASIS, j = idx % NBASIS;
    const float4* ra = (const float4*)((i < NB) ? (bubbles + i * D)
                                                : (E + (long)tokens[i - NB] * D));
    const float4* rb = (const float4*)((j < NB) ? (bubbles + j * D)
                                                : (E + (long)tokens[j - NB] * D));
    float a0 = 0.f, a1 = 0.f, a2 = 0.f, a3 = 0.f;
    #pragma unroll
    for (int k = 0; k < D / 4; k += 4) {
        float4 x, y;
        x = ra[k];     y = rb[k];
        a0 = fmaf(x.x, y.x, fmaf(x.y, y.y, fmaf(x.z, y.z, fmaf(x.w, y.w, a0))));
        x = ra[k + 1]; y = rb[k + 1];
        a1 = fmaf(x.x, y.x, fmaf(x.y, y.y, fmaf(x.z, y.z, fmaf(x.w, y.w, a1))));
        x = ra[k + 2]; y = rb[k + 2];
        a2 = fmaf(x.x, y.x, fmaf(x.y, y.y, fmaf(x.z, y.z, fmaf(x.w, y.w, a2))));
        x = ra[k + 3]; y = rb[k + 3];
        a3 = fmaf(x.x, y.x, fmaf(x.y, y.y, fmaf(x.z, y.z, fmaf(x.w, y.w, a3))));
    }
    ws[WS_S + i * NBASIS + j] = (a0 + a1) + (a2 + a3);
}

// ---------------------------------------------------------------------------
// Fast cross-lane / math primitives
// ---------------------------------------------------------------------------
template <int CTRL>
__device__ __forceinline__ float dpp_add(float x) {
    int yi = __builtin_amdgcn_update_dpp(0, __float_as_int(x), CTRL, 0xF, 0xF, true);
    return x + __int_as_float(yi);
}
// all-lane sum over each 32-lane group: xor1,xor2 (quad_perm), ror4, ror8, xor16
__device__ __forceinline__ float sum32(float x) {
    x = dpp_add<0xB1>(x);    // quad_perm [1,0,3,2]  == xor 1
    x = dpp_add<0x4E>(x);    // quad_perm [2,3,0,1]  == xor 2
    x = dpp_add<0x124>(x);   // row_ror:4
    x = dpp_add<0x128>(x);   // row_ror:8
    int yi = __builtin_amdgcn_ds_swizzle(__float_as_int(x), 0x401F);  // xor 16
    return x + __int_as_float(yi);
}
__device__ __forceinline__ float rdlane(float v, int lane) {
    return __int_as_float(__builtin_amdgcn_readlane(__float_as_int(v), lane));
}
// native 1-ulp reciprocal / sqrt (avoid IEEE div/sqrt expansion, ~12 instr each)
__device__ __forceinline__ float fast_rcp(float x) {
    float r; asm("v_rcp_f32 %0, %1" : "=v"(r) : "v"(x)); return r;
}
__device__ __forceinline__ float fast_sqrt(float x) {
    float r; asm("v_sqrt_f32 %0, %1" : "=v"(r) : "v"(x)); return r;
}

// ---------------------------------------------------------------------------
// K2: sequential scan, single wave, register-resident state.
// Issue-bound (1 wave): minimize instruction count.
// ---------------------------------------------------------------------------
__global__ __launch_bounds__(64) void foam_scan3(
    const float* __restrict__ p_mdb, const float* __restrict__ p_ns,
    float* __restrict__ ws)
{
    const int l = threadIdx.x;
    const int b = l & 31;

    __shared__ float S2[SEQ][NBASIS];   // S2[t][i] = S[32+t][i]  (24.5 KB)

    const float* wsS = ws + WS_S;
    for (int e = l; e < SEQ * NBASIS / 4; e += 64)
        ((float4*)S2)[e] = ((const float4*)(wsS + NB * NBASIS))[e];

    float gbb_row[NB];   // S[b][j], j<32
    float gxb_row[NB];   // S[32+l][j], j<32
    {
        const float4* pa = (const float4*)(wsS + b * NBASIS);
        const float4* pb = (const float4*)(wsS + (NB + l) * NBASIS);
        #pragma unroll
        for (int i = 0; i < 8; ++i) {
            float4 va = pa[i], vb = pb[i];
            gbb_row[4*i] = va.x; gbb_row[4*i+1] = va.y; gbb_row[4*i+2] = va.z; gbb_row[4*i+3] = va.w;
            gxb_row[4*i] = vb.x; gxb_row[4*i+1] = vb.y; gxb_row[4*i+2] = vb.z; gxb_row[4*i+3] = vb.w;
        }
    }
    const float diag = wsS[(NB + l) * NBASIS + NB + l];   // |x_l|^2
    const float bn2  = wsS[b * NBASIS + b];               // |bub_b|^2

    const float mdb  = p_mdb[0];
    const float sens = fabsf(p_ns[0]);
    const float scale = 0.0625f;

    __syncthreads();

    float z = 0.f, y = 0.f, mm2 = 0.f;
    float m1 = 0.f, m2 = 0.f;

    float* wsCOEF = ws + WS_COEF;
    float* wsU    = ws + WS_U;
    float* wsVV   = ws + WS_VV;
    float* wsC    = ws + WS_C;

    float gxcol = S2[0][b];
    float xxcol = S2[0][NB + l];

    #pragma unroll 2
    for (int t = 0; t < SEQ; ++t) {
        // ---- scalars for this token ----
        const float xdm = rdlane(z, t);
        const float px  = rdlane(diag, t);
        // nov = 1 - xdm/((sqrt(px)+eps)(sqrt(mm2)+eps)) ~= 1 - xdm*rcp(sqrt(px*mm2))
        const float nov = (mm2 > 9.8e-17f)
                        ? (1.f - xdm * fast_rcp(fast_sqrt(px * mm2)))
                        : 1.f;
        const float decay = fast_rcp(1.f + __expf(sens * nov - mdb));
        const float omd = 1.f - decay;

        // emit x_wm coefficients (OLD m)
        wsCOEF[t * NBASIS + l] = fmaf(decay, m1, (l == NB + t) ? 1.f : 0.f);
        if (l < NB)
            wsCOEF[t * NBASIS + 64 + l] = fmaf(decay, m2, (64 + l == NB + t) ? 1.f : 0.f);

        const float q = px + 2.f * decay * xdm + decay * decay * mm2;
        const float c = fmaf(decay, y, gxcol);

        // prefetch next token's Gram column
        const int tn = (t + 1) & (SEQ - 1);
        const float gxn = S2[tn][b];
        const float xxn = S2[tn][NB + l];

        // ---- 6 softmax rounds, closed-form equilibrium ----
        const float cq = (c - q) * scale;
        const float qs = q * scale;
        float alpha = 1.f, w = 0.f;
        #pragma unroll
        for (int k = 0; k <= NEQ; ++k) {
            float dv = fmaf(alpha, cq, qs);
            float ev = __expf(dv);
            float sm = sum32(ev);
            w = ev * fast_rcp(sm);
            if (k < NEQ) alpha *= (1.f - w);
        }
        const float p = w;

        // ---- per-bubble outputs ----
        const float oma = 1.f - alpha;
        const float s2v = alpha * alpha * bn2 + 2.f * alpha * oma * c + oma * oma * q;
        // g = p/(sqrt(s2v)+1e-10)^2 ~= p * rcp(s2v + 1e-20)
        const float g = p * fast_rcp(s2v + 1e-20f);
        if (l < NB) wsU[t * NB + b]  = g * alpha * alpha;
        else        wsVV[t * NB + b] = 2.f * g * alpha * oma;

        // ---- broadcast alphas to SGPRs ----
        float asg[NB];
        #pragma unroll
        for (int j = 0; j < NB; ++j) asg[j] = rdlane(alpha, j);

        float ga0 = 0.f, ga1 = 0.f, ga2 = 0.f, ga3 = 0.f;
        float da0 = 0.f, da1 = 0.f, da2 = 0.f, da3 = 0.f;
        #pragma unroll
        for (int j = 0; j < NB; j += 4) {
            ga0 = fmaf(gbb_row[j],     asg[j],     ga0);
            ga1 = fmaf(gbb_row[j + 1], asg[j + 1], ga1);
            ga2 = fmaf(gbb_row[j + 2], asg[j + 2], ga2);
            ga3 = fmaf(gbb_row[j + 3], asg[j + 3], ga3);
            da0 = fmaf(gxb_row[j],     asg[j],     da0);
            da1 = fmaf(gxb_row[j + 1], asg[j + 1], da1);
            da2 = fmaf(gxb_row[j + 2], asg[j + 2], da2);
            da3 = fmaf(gxb_row[j + 3], asg[j + 3], da3);
        }
        const float ga  = (ga0 + ga1) + (ga2 + ga3);   // (G_BB . alpha)_b
        const float dar = (da0 + da1) + (da2 + da3);   // (Gx_row . alpha)_l

        // ---- reductions over bubbles ----
        const float r0 = sum32(alpha);
        const float r1 = sum32(alpha * c);
        const float r2 = sum32(alpha * y);
        const float r3 = sum32(alpha * ga);
        const float Cp = sum32(g * oma * oma);
        if (l == 0) wsC[t] = Cp;

        // ---- state update (same algebra as verified scan2) ----
        const float msc = (32.f - r0) * (1.f / 32.f);
        const float k1 = decay * fmaf(omd, msc, 1.f);
        const float mmxwm = fmaf(decay, mm2, xdm);
        const float mmms = fmaf(msc, mmxwm, r2 * (1.f / 32.f));
        const float u1sq = r3 * (1.f / 1024.f);
        const float msms = fmaf(msc * msc, q, fmaf(2.f * msc, r1 * (1.f / 32.f), u1sq));
        mm2 = decay * decay * mm2 + 2.f * decay * omd * mmms + omd * omd * msms;

        z = fmaf(k1, z, omd * fmaf(msc, xxcol, dar * (1.f / 32.f)));
        y = fmaf(k1, y, omd * fmaf(msc, gxcol, ga  * (1.f / 32.f)));

        const float inc1 = (l < NB) ? omd * alpha * (1.f / 32.f)
                                    : ((l == NB + t) ? omd * msc : 0.f);
        m1 = fmaf(k1, m1, inc1);
        m2 = fmaf(k1, m2, (l == t - NB) ? omd * msc : 0.f);

        gxcol = gxn;
        xxcol = xxn;
    }
}

// ---------------------------------------------------------------------------
// K3: reconstruct x_wm[t][d]
// ---------------------------------------------------------------------------
__global__ __launch_bounds__(256) void foam_recon(
    const int* __restrict__ tokens, const float* __restrict__ E,
    const float* __restrict__ bubbles, float* __restrict__ ws)
{
    const int t = blockIdx.x;
    const int d = threadIdx.x;
    __shared__ float cf[NBASIS];
    __shared__ int stok[SEQ];
    if (d < NBASIS) cf[d] = ws[WS_COEF + t * NBASIS + d];
    if (d < SEQ) stok[d] = tokens[d];
    __syncthreads();
    float acc = 0.f;
    #pragma unroll 8
    for (int bb = 0; bb < NB; ++bb) acc = fmaf(cf[bb], bubbles[bb * D + d], acc);
    #pragma unroll 8
    for (int j = 0; j < SEQ; ++j) acc = fmaf(cf[32 + j], E[(long)stok[j] * D + d], acc);
    ws[WS_XWM + t * D + d] = acc;
}

// ---------------------------------------------------------------------------
// K4: MFMA split-bf16 GEMM H = E @ [bub; xwm]^T + fused Born-rule epilogue.
// ---------------------------------------------------------------------------
#define MROWS 32
#define HS 100
#define US 36

__device__ __forceinline__ void split_bf16(const float* p, short8v& hi, short8v& lo) {
    float4 f0 = *(const float4*)p;
    float4 f1 = *(const float4*)(p + 4);
    float f[8] = {f0.x, f0.y, f0.z, f0.w, f1.x, f1.y, f1.z, f1.w};
    #pragma unroll
    for (int j = 0; j < 8; ++j) {
        unsigned xb = __builtin_bit_cast(unsigned, f[j]);
        unsigned hb = xb & 0xFFFF0000u;
        float fl = f[j] - __builtin_bit_cast(float, hb);
        unsigned lb = __builtin_bit_cast(unsigned, fl);
        hi[j] = (short)(hb >> 16);
        lo[j] = (short)(lb >> 16);
    }
}

__global__ __launch_bounds__(512, 4) void foam_mfma_logits(
    const float* __restrict__ E,
    const float* __restrict__ bubbles,
    const float* __restrict__ ws,
    float* __restrict__ out)
{
    __shared__ float H[MROWS][HS];
    __shared__ float us[SEQ * US];
    __shared__ float vs[SEQ * US];
    __shared__ float Cs[SEQ];

    const int tid = threadIdx.x;
    const int w = tid >> 6;
    const int l = tid & 63;
    const int lm = l & 15;
    const int lq = l >> 4;

    for (int i = tid; i < SEQ * NB; i += 512) {
        int t = i >> 5, bb = i & 31;
        us[t * US + bb] = ws[WS_U + i];
        vs[t * US + bb] = ws[WS_VV + i];
    }
    if (tid < SEQ) Cs[tid] = ws[WS_C + tid];

    const long vb = (long)blockIdx.x * MROWS;

    if (w < 6) {
        short8v bhi[8], blo[8];
        const int n = w * 16 + lm;
        const float* wrow = (w < 2) ? (bubbles + n * D)
                                    : (ws + WS_XWM + (n - 32) * D);
        #pragma unroll
        for (int ks = 0; ks < 8; ++ks)
            split_bf16(wrow + ks * 32 + lq * 8, bhi[ks], blo[ks]);

        #pragma unroll
        for (int mt = 0; mt < 2; ++mt) {
            f32x4 acc = {0.f, 0.f, 0.f, 0.f};
            const float* arow = E + (vb + mt * 16 + lm) * D + lq * 8;
            #pragma unroll
            for (int ks = 0; ks < 8; ++ks) {
                short8v ahi, alo;
                split_bf16(arow + ks * 32, ahi, alo);
                acc = __builtin_amdgcn_mfma_f32_16x16x32_bf16(ahi, bhi[ks], acc, 0, 0, 0);
                acc = __builtin_amdgcn_mfma_f32_16x16x32_bf16(ahi, blo[ks], acc, 0, 0, 0);
                acc = __builtin_amdgcn_mfma_f32_16x16x32_bf16(alo, bhi[ks], acc, 0, 0, 0);
            }
            #pragma unroll
            for (int r = 0; r < 4; ++r)
                H[mt * 16 + lq * 4 + r][w * 16 + lm] = acc[r];
        }
    }
    __syncthreads();

    const int t0 = w * 8 + lq;
    const int t1 = t0 + 4;
    const float c0 = Cs[t0], c1 = Cs[t1];

    #pragma unroll
    for (int mt = 0; mt < 2; ++mt) {
        const int row = mt * 16 + lm;
        float G[NB], G2[NB];
        #pragma unroll
        for (int i = 0; i < 8; ++i)
            *(float4*)&G[4 * i] = *(const float4*)&H[row][4 * i];
        #pragma unroll
        for (int i = 0; i < NB; ++i) G2[i] = G[i] * G[i];

        float a0 = 0.f, b0 = 0.f, a1 = 0.f, b1 = 0.f;
        #pragma unroll
        for (int i = 0; i < 8; ++i) {
            float4 u0 = *(const float4*)&us[t0 * US + 4 * i];
            float4 v0 = *(const float4*)&vs[t0 * US + 4 * i];
            float4 u1 = *(const float4*)&us[t1 * US + 4 * i];
            float4 v1 = *(const float4*)&vs[t1 * US + 4 * i];
            a0 = fmaf(u0.x, G2[4*i], fmaf(u0.y, G2[4*i+1], fmaf(u0.z, G2[4*i+2], fmaf(u0.w, G2[4*i+3], a0))));
            b0 = fmaf(v0.x, G[4*i],  fmaf(v0.y, G[4*i+1],  fmaf(v0.z, G[4*i+2],  fmaf(v0.w, G[4*i+3],  b0))));
            a1 = fmaf(u1.x, G2[4*i], fmaf(u1.y, G2[4*i+1], fmaf(u1.z, G2[4*i+2], fmaf(u1.w, G2[4*i+3], a1))));
            b1 = fmaf(v1.x, G[4*i],  fmaf(v1.y, G[4*i+1],  fmaf(v1.z, G[4*i+2],  fmaf(v1.w, G[4*i+3],  b1))));
        }
        const float h0 = H[row][32 + t0];
        const float h1 = H[row][32 + t1];
        out[(long)t0 * VOCAB + vb + row] = fmaf(h0, b0, fmaf(h0 * h0, c0, a0));
        out[(long)t1 * VOCAB + vb + row] = fmaf(h1, b1, fmaf(h1 * h1, c1, a1));
    }
}

extern "C" void kernel_launch(void* const* d_in, const int* in_sizes, int n_in,
                              void* d_out, int out_size, void* d_ws, size_t ws_size,
                              hipStream_t stream) {
    const int*   tokens  = (const int*)d_in[0];
    const float* E       = (const float*)d_in[1];
    const float* bubbles = (const float*)d_in[2];
    const float* mdb     = (const float*)d_in[3];
    const float* ns      = (const float*)d_in[4];
    float* out = (float*)d_out;
    float* ws  = (float*)d_ws;

    hipLaunchKernelGGL(foam_grams, dim3((NBASIS * NBASIS) / 256), dim3(256), 0, stream,
                       tokens, E, bubbles, ws);
    hipLaunchKernelGGL(foam_scan3, dim3(1), dim3(64), 0, stream, mdb, ns, ws);
    hipLaunchKernelGGL(foam_recon, dim3(SEQ), dim3(256), 0, stream,
                       tokens, E, bubbles, ws);
    hipLaunchKernelGGL(foam_mfma_logits, dim3(VOCAB / MROWS), dim3(512), 0, stream,
                       E, bubbles, ws, out);
}